// Round 6
// baseline (195.116 us; speedup 1.0000x reference)
//
#include <hip/hip_runtime.h>

#define NN 2048
#define MLPW 16

typedef __attribute__((ext_vector_type(8))) short short8v;
typedef __attribute__((ext_vector_type(16))) float float16v;
typedef __attribute__((ext_vector_type(4))) unsigned short ushort4v;
typedef __attribute__((ext_vector_type(8))) unsigned short ushort8v;

__device__ __forceinline__ unsigned short f2b(float f) {
  unsigned int u = __float_as_uint(f);
  unsigned int r = (u + 0x7fffu + ((u >> 16) & 1u)) >> 16;  // RNE
  return (unsigned short)r;
}
__device__ __forceinline__ float b2f(unsigned short u) {
  return __uint_as_float(((unsigned int)u) << 16);
}

// ---------------- K1: edge MLP -> Abf16 (+I), dr, fused column partials ------
// 256 blocks x 8 rows. Thread owns cols j0..j0+7 for all 8 rows; accumulates
// column partials in registers -> partial[256][2048] (replaces colsum pass).
__global__ void __launch_bounds__(256) edge_kernel(
    const float* __restrict__ adj, const float* __restrict__ xdeg,
    const float* __restrict__ ydeg,
    const float* __restrict__ Wm1, const float* __restrict__ bm1,
    const float* __restrict__ Wm2, const float* __restrict__ bm2,
    unsigned short* __restrict__ Abf, float* __restrict__ dr,
    float* __restrict__ partial) {
  __shared__ float w1[48], b1[16], w2[32], b2s[2];
  __shared__ float wsum[8][4];
  const int tid = threadIdx.x;
  if (tid < 48) w1[tid] = Wm1[tid];
  if (tid < 16) b1[tid] = bm1[tid];
  if (tid < 32) w2[tid] = Wm2[tid];
  if (tid < 2) b2s[tid] = bm2[tid];
  __syncthreads();
  const int i0 = blockIdx.x * 8;
  const int j0 = tid * 8;
  const int lane = tid & 63, wave = tid >> 6;
  float cacc[8] = {0, 0, 0, 0, 0, 0, 0, 0};
#pragma unroll
  for (int r = 0; r < 8; r++) {
    const int i = i0 + r;
    const float* ap = adj + (size_t)i * NN + j0;
    const float* xp = xdeg + (size_t)i * NN + j0;
    const float* yp = ydeg + (size_t)i * NN + j0;
    float4 a0 = ((const float4*)ap)[0], a1 = ((const float4*)ap)[1];
    float4 x0 = ((const float4*)xp)[0], x1 = ((const float4*)xp)[1];
    float4 y0 = ((const float4*)yp)[0], y1 = ((const float4*)yp)[1];
    const float aa[8] = {a0.x, a0.y, a0.z, a0.w, a1.x, a1.y, a1.z, a1.w};
    const float xx[8] = {x0.x, x0.y, x0.z, x0.w, x1.x, x1.y, x1.z, x1.w};
    const float yy[8] = {y0.x, y0.y, y0.z, y0.w, y1.x, y1.y, y1.z, y1.w};
    ushort8v oo;
    float rs = 0.f;
#pragma unroll
    for (int e = 0; e < 8; e++) {
      float l0 = b2s[0], l1 = b2s[1];
#pragma unroll
      for (int k = 0; k < MLPW; k++) {
        float h = fmaf(aa[e], w1[k], fmaf(xx[e], w1[16 + k], fmaf(yy[e], w1[32 + k], b1[k])));
        h = fmaxf(h, 0.f);
        l0 = fmaf(h, w2[2 * k], l0);
        l1 = fmaf(h, w2[2 * k + 1], l1);
      }
      float mask = 1.f / (1.f + __expf(l0 - l1));  // softmax[...,1]
      float v = aa[e] * mask;
      if (j0 + e == i) v += 1.f;
      oo[e] = f2b(v);
      rs += v;
      cacc[e] += v;
    }
    *(ushort8v*)&Abf[(size_t)i * NN + j0] = oo;
#pragma unroll
    for (int off = 32; off > 0; off >>= 1) rs += __shfl_down(rs, off);
    if (lane == 0) wsum[r][wave] = rs;
  }
  float* pp = partial + (size_t)blockIdx.x * NN + j0;
  *(float4*)pp = make_float4(cacc[0], cacc[1], cacc[2], cacc[3]);
  *(float4*)(pp + 4) = make_float4(cacc[4], cacc[5], cacc[6], cacc[7]);
  __syncthreads();
  if (tid < 8) {
    float t = wsum[tid][0] + wsum[tid][1] + wsum[tid][2] + wsum[tid][3];
    dr[i0 + tid] = t > 0.f ? rsqrtf(t) : 0.f;
  }
}

// ---------------- K3: dc = rsqrt(sum of 256 col partials) --------------------
__global__ void __launch_bounds__(256) dc_kernel(
    const float* __restrict__ partial, float* __restrict__ dc) {
  const int j = blockIdx.x * 256 + threadIdx.x;
  float s = 0.f;
#pragma unroll 4
  for (int p = 0; p < 256; p++) s += partial[(size_t)p * NN + j];
  dc[j] = s > 0.f ? rsqrtf(s) : 0.f;
}

// ---------------- split-K MFMA GEMM ------------------------------------------
// P[sk][m][n] = sum_{k in chunk sk} A[m][k] * B[n][k]
// A: bf16 [M][K], or (A_F32T) fp32 [K][lda] read transposed (A[m][k]=Av[k*lda+row0+m]).
// B: bf16 [N][K], or (B_F32) fp32 [N][K] (converted during staging).
// Block: BM=32 x BN=128, inner KC=128; 4 waves, one 32x32x16 mfma tile each.
// LDS stride 136 ushorts = 68 dwords == 4 (mod 32): frag ds_read_b128 hits each
// bank exactly 4x (conflict-minimal), rows 16B-aligned (272 = 17*16).
template <bool A_F32T, bool B_F32>
__global__ void __launch_bounds__(256) gemm_splitk_kernel(
    const void* __restrict__ Av, const void* __restrict__ Bv,
    float* __restrict__ P, int M, int N, int K, int Kc, int lda) {
  constexpr int SW = 136;
  __shared__ unsigned short As[32 * SW];
  __shared__ unsigned short Bs[128 * SW];
  const int tid = threadIdx.x;
  const int lane = tid & 63, wave = tid >> 6;
  const int l31 = lane & 31, half = lane >> 5;
  const int row0 = blockIdx.y * 32, col0 = blockIdx.x * 128;
  const int kbeg = blockIdx.z * Kc;

  float16v acc;
#pragma unroll
  for (int r = 0; r < 16; r++) acc[r] = 0.f;

  for (int k0 = 0; k0 < Kc; k0 += 128) {
    // ---- stage A tile: 32 rows(m) x 128 k
    if (A_F32T) {
      // source fp32 [K][lda], transpose in-flight. thread: k-row tid>>1, 16 cols.
      const int kidx = tid >> 1, nh = (tid & 1) * 16;
      const float* src = (const float*)Av + (size_t)(kbeg + k0 + kidx) * lda + row0 + nh;
      float4 v0 = ((const float4*)src)[0], v1 = ((const float4*)src)[1];
      float4 v2 = ((const float4*)src)[2], v3 = ((const float4*)src)[3];
      const float vv[16] = {v0.x, v0.y, v0.z, v0.w, v1.x, v1.y, v1.z, v1.w,
                            v2.x, v2.y, v2.z, v2.w, v3.x, v3.y, v3.z, v3.w};
#pragma unroll
      for (int e = 0; e < 16; e++) As[(nh + e) * SW + kidx] = f2b(vv[e]);
    } else {
      const unsigned short* Ab = (const unsigned short*)Av;
#pragma unroll
      for (int i = 0; i < 2; i++) {
        const int id = tid + i * 256;
        const int r = id >> 4, c = id & 15;
        *(ushort8v*)&As[r * SW + c * 8] =
            *(const ushort8v*)&Ab[(size_t)(row0 + r) * K + kbeg + k0 + c * 8];
      }
    }
    // ---- stage B panel: 128 rows(n) x 128 k = 2048 8-ushort chunks, 8/thread
#pragma unroll
    for (int i = 0; i < 8; i++) {
      const int id = tid + i * 256;
      const int r = id >> 4, c = id & 15;
      if (B_F32) {
        const float* bp = (const float*)Bv + (size_t)(col0 + r) * K + kbeg + k0 + c * 8;
        float4 u = *(const float4*)bp, v = *(const float4*)(bp + 4);
        ushort8v pk = {f2b(u.x), f2b(u.y), f2b(u.z), f2b(u.w),
                       f2b(v.x), f2b(v.y), f2b(v.z), f2b(v.w)};
        *(ushort8v*)&Bs[r * SW + c * 8] = pk;
      } else {
        *(ushort8v*)&Bs[r * SW + c * 8] =
            *(const ushort8v*)&((const unsigned short*)Bv)[(size_t)(col0 + r) * K + kbeg + k0 + c * 8];
      }
    }
    __syncthreads();
    // A frag: m=lane&31, k=(lane>>5)*8+j ; B frag: n=lane&31, same k
#pragma unroll
    for (int ks = 0; ks < 8; ks++) {
      short8v a = *(const short8v*)&As[l31 * SW + ks * 16 + half * 8];
      short8v b = *(const short8v*)&Bs[(wave * 32 + l31) * SW + ks * 16 + half * 8];
      acc = __builtin_amdgcn_mfma_f32_32x32x16_bf16(a, b, acc, 0, 0, 0);
    }
    __syncthreads();
  }
  // C/D: col = lane&31, row = (reg&3) + 8*(reg>>2) + 4*(lane>>5)
  float* Pb = P + ((size_t)blockIdx.z * M + row0) * N + col0 + wave * 32 + l31;
#pragma unroll
  for (int reg = 0; reg < 16; reg++) {
    const int m = (reg & 3) + 8 * (reg >> 2) + 4 * half;
    Pb[(size_t)m * N] = acc[reg];
  }
}

// ---------------- reduce GEMM1 partials -> XWT bf16 [256][2048], *dc[col] ----
__global__ void __launch_bounds__(256) reduce_xwt_kernel(
    const float* __restrict__ P, const float* __restrict__ dc,
    unsigned short* __restrict__ XWT) {
  const int t = blockIdx.x * 256 + threadIdx.x;
  const int i = t >> 8;            // output row (0..255)
  const int j0 = (t & 255) * 8;    // output col group
  float s[8] = {0, 0, 0, 0, 0, 0, 0, 0};
#pragma unroll
  for (int sk = 0; sk < 4; sk++) {
    const float* p = P + ((size_t)sk * 256 + i) * 2048 + j0;
    float4 u = *(const float4*)p, v = *(const float4*)(p + 4);
    s[0] += u.x; s[1] += u.y; s[2] += u.z; s[3] += u.w;
    s[4] += v.x; s[5] += v.y; s[6] += v.z; s[7] += v.w;
  }
  float4 d0 = *(const float4*)&dc[j0], d1 = *(const float4*)&dc[j0 + 4];
  ushort8v o = {f2b(s[0] * d0.x), f2b(s[1] * d0.y), f2b(s[2] * d0.z), f2b(s[3] * d0.w),
                f2b(s[4] * d1.x), f2b(s[5] * d1.y), f2b(s[6] * d1.z), f2b(s[7] * d1.w)};
  *(ushort8v*)&XWT[(size_t)i * 2048 + j0] = o;
}

// ---------------- fused tail: P2 -> T1(=dr*sum) -> hid(@Wl2+bl2) -> HW(@Wg2*dc)
__global__ void __launch_bounds__(256) tail_kernel(
    const float* __restrict__ P2, const float* __restrict__ dr,
    const float* __restrict__ dc, const float* __restrict__ Wl2,
    const float* __restrict__ bl2, const float* __restrict__ Wg2,
    float* __restrict__ hid, float* __restrict__ HW) {
  __shared__ float T1s[16][256];
  __shared__ float hidS[16][68];
  const int m0 = blockIdx.x * 16;
  const int tid = threadIdx.x;
  // phase 1: T1 rows (reduce 4 split-K partials, scale by dr)
#pragma unroll
  for (int i = 0; i < 16; i++) {
    const int idx = tid + i * 256;
    const int mi = idx >> 8, n = idx & 255;
    float s = 0.f;
#pragma unroll
    for (int sk = 0; sk < 4; sk++)
      s += P2[((size_t)sk * 2048 + m0 + mi) * 256 + n];
    T1s[mi][n] = s * dr[m0 + mi];
  }
  __syncthreads();
  // phase 2: hid[m][j] = T1[m][:] @ Wl2[:,j] + bl2[j]
  const int j = tid & 63, mg = tid >> 6;
  float h[4] = {bl2[j], bl2[j], bl2[j], bl2[j]};
  for (int n = 0; n < 256; n++) {
    float w = Wl2[(size_t)n * 64 + j];
#pragma unroll
    for (int r = 0; r < 4; r++) h[r] = fmaf(T1s[mg * 4 + r][n], w, h[r]);
  }
#pragma unroll
  for (int r = 0; r < 4; r++) {
    hid[(size_t)(m0 + mg * 4 + r) * 64 + j] = h[r];
    hidS[mg * 4 + r][j] = h[r];
  }
  __syncthreads();
  // phase 3: HW[m][c] = dc[m] * hid[m][:] @ Wg2[:,c]
  if (tid < 64) {
    const int r = tid >> 2, c = tid & 3;
    float s = 0.f;
#pragma unroll
    for (int jj = 0; jj < 64; jj++) s = fmaf(hidS[r][jj], Wg2[jj * 4 + c], s);
    HW[(size_t)(m0 + r) * 4 + c] = s * dc[m0 + r];
  }
}

// ---------------- out[i,:] = dr[i] * (Abf[i,:] @ HW) -------------------------
__global__ void __launch_bounds__(256) out_kernel(
    const unsigned short* __restrict__ Abf, const float* __restrict__ HW,
    const float* __restrict__ dr, float* __restrict__ outp) {
  const int i = blockIdx.x, tid = threadIdx.x;
  const ushort8v a8 = ((const ushort8v*)(Abf + (size_t)i * NN))[tid];
  const float4* hw4 = (const float4*)HW;
  const int j0 = tid * 8;
  float ax = 0.f, ay = 0.f, az = 0.f, aw = 0.f;
#pragma unroll
  for (int e = 0; e < 8; e++) {
    float a = b2f(a8[e]);
    float4 h = hw4[j0 + e];
    ax = fmaf(a, h.x, ax);
    ay = fmaf(a, h.y, ay);
    az = fmaf(a, h.z, az);
    aw = fmaf(a, h.w, aw);
  }
  __shared__ float red[4][256];
  red[0][tid] = ax; red[1][tid] = ay; red[2][tid] = az; red[3][tid] = aw;
  __syncthreads();
  for (int s = 128; s > 0; s >>= 1) {
    if (tid < s) {
      red[0][tid] += red[0][tid + s];
      red[1][tid] += red[1][tid + s];
      red[2][tid] += red[2][tid + s];
      red[3][tid] += red[3][tid + s];
    }
    __syncthreads();
  }
  if (tid < 4) outp[(size_t)i * 4 + tid] = dr[i] * red[tid][0];
}

extern "C" void kernel_launch(void* const* d_in, const int* in_sizes, int n_in,
                              void* d_out, int out_size, void* d_ws, size_t ws_size,
                              hipStream_t stream) {
  const float* x    = (const float*)d_in[0];
  const float* adj  = (const float*)d_in[1];
  const float* xdeg = (const float*)d_in[2];
  const float* ydeg = (const float*)d_in[3];
  const float* Wm1  = (const float*)d_in[4];
  const float* bm1  = (const float*)d_in[5];
  const float* Wm2  = (const float*)d_in[6];
  const float* bm2  = (const float*)d_in[7];
  const float* Wg1  = (const float*)d_in[8];
  const float* Wl2  = (const float*)d_in[9];
  const float* bl2  = (const float*)d_in[10];
  const float* Wg2  = (const float*)d_in[11];

  char* ws = (char*)d_ws;
  unsigned short* Abf  = (unsigned short*)(ws);              // 8 MiB [2048][2048]
  unsigned short* XWT  = (unsigned short*)(ws + 8388608);    // 1 MiB [256][2048]
  float* P    = (float*)(ws + 9437184);                      // 8 MiB split-K partials
  float* part = (float*)(ws + 17825792);                     // 2 MiB [256][2048]
  float* dr   = (float*)(ws + 19922944);
  float* dc   = (float*)(ws + 19931136);
  float* HW   = (float*)(ws + 19939328);                     // 32 KiB

  float* outp = (float*)d_out;             // output 0: [2048,4]
  float* hid  = (float*)d_out + 2048 * 4;  // output 1: [2048,64]

  // edge MLP -> Abf (+I), dr, fused column partials
  edge_kernel<<<NN / 8, 256, 0, stream>>>(adj, xdeg, ydeg, Wm1, bm1, Wm2, bm2,
                                          Abf, dr, part);
  dc_kernel<<<NN / 256, 256, 0, stream>>>(part, dc);
  // GEMM1: P[sk][i][j] partial of Wg1^T @ x^T  (M=256, N=2048, K=1024, SK=4)
  // A staged straight from fp32 Wg1 [1024][256] with in-LDS transpose.
  gemm_splitk_kernel<true, true><<<dim3(2048 / 128, 256 / 32, 4), 256, 0, stream>>>(
      Wg1, x, P, 256, 2048, 1024, 256, 256);
  reduce_xwt_kernel<<<256, 256, 0, stream>>>(P, dc, XWT);
  // GEMM2: P[sk][m][n] partial of Abf @ XWT^T  (M=2048, N=256, K=2048, SK=4)
  gemm_splitk_kernel<false, false><<<dim3(256 / 128, 2048 / 32, 4), 256, 0, stream>>>(
      Abf, XWT, P, 2048, 256, 2048, 512, 0);
  // tail: reduce + dr scale -> hid (d_out) and HW (= dc * hid @ Wg2)
  tail_kernel<<<2048 / 16, 256, 0, stream>>>(P, dr, dc, Wl2, bl2, Wg2, hid, HW);
  out_kernel<<<NN, 256, 0, stream>>>(Abf, HW, dr, outp);
}

// Round 7
// 179.009 us; speedup vs baseline: 1.0900x; 1.0900x over previous
//
#include <hip/hip_runtime.h>

#define NN 2048
#define MLPW 16

typedef __attribute__((ext_vector_type(8))) short short8v;
typedef __attribute__((ext_vector_type(16))) float float16v;
typedef __attribute__((ext_vector_type(4))) unsigned short ushort4v;
typedef __attribute__((ext_vector_type(8))) unsigned short ushort8v;

__device__ __forceinline__ unsigned short f2b(float f) {
  unsigned int u = __float_as_uint(f);
  unsigned int r = (u + 0x7fffu + ((u >> 16) & 1u)) >> 16;  // RNE
  return (unsigned short)r;
}
__device__ __forceinline__ float b2f(unsigned short u) {
  return __uint_as_float(((unsigned int)u) << 16);
}

// ---------------- K1: edge MLP -> Abf16 (unnormalized, +I), dr ---------------
// grid 2048 (8 blocks/CU): HBM-bound, needs the occupancy for latency hiding.
__global__ void __launch_bounds__(256) edge_kernel(
    const float* __restrict__ adj, const float* __restrict__ xdeg,
    const float* __restrict__ ydeg,
    const float* __restrict__ Wm1, const float* __restrict__ bm1,
    const float* __restrict__ Wm2, const float* __restrict__ bm2,
    unsigned short* __restrict__ Abf, float* __restrict__ dr) {
  __shared__ float w1[48], b1[16], w2[32], b2s[2];
  __shared__ float wsum[4];
  const int tid = threadIdx.x;
  if (tid < 48) w1[tid] = Wm1[tid];
  if (tid < 16) b1[tid] = bm1[tid];
  if (tid < 32) w2[tid] = Wm2[tid];
  if (tid < 2) b2s[tid] = bm2[tid];
  __syncthreads();
  const int i = blockIdx.x;
  const float4* adj4 = (const float4*)(adj + (size_t)i * NN);
  const float4* xd4 = (const float4*)(xdeg + (size_t)i * NN);
  const float4* yd4 = (const float4*)(ydeg + (size_t)i * NN);
  ushort4v* A4 = (ushort4v*)(Abf + (size_t)i * NN);
  float rsum = 0.f;
  for (int j4 = tid; j4 < NN / 4; j4 += 256) {
    float4 av = adj4[j4], xv = xd4[j4], yv = yd4[j4];
    float aa[4] = {av.x, av.y, av.z, av.w};
    float xx[4] = {xv.x, xv.y, xv.z, xv.w};
    float yy[4] = {yv.x, yv.y, yv.z, yv.w};
    ushort4v oo;
#pragma unroll
    for (int e = 0; e < 4; e++) {
      float l0 = b2s[0], l1 = b2s[1];
#pragma unroll
      for (int k = 0; k < MLPW; k++) {
        float h = fmaf(aa[e], w1[k], fmaf(xx[e], w1[16 + k], fmaf(yy[e], w1[32 + k], b1[k])));
        h = fmaxf(h, 0.f);
        l0 = fmaf(h, w2[2 * k], l0);
        l1 = fmaf(h, w2[2 * k + 1], l1);
      }
      float mask = 1.f / (1.f + __expf(l0 - l1));  // softmax[...,1]
      float v = aa[e] * mask;
      int j = j4 * 4 + e;
      if (j == i) v += 1.f;
      oo[e] = f2b(v);
      rsum += v;
    }
    A4[j4] = oo;
  }
#pragma unroll
  for (int off = 32; off > 0; off >>= 1) rsum += __shfl_down(rsum, off);
  if ((tid & 63) == 0) wsum[tid >> 6] = rsum;
  __syncthreads();
  if (tid == 0) {
    float t = wsum[0] + wsum[1] + wsum[2] + wsum[3];
    dr[i] = t > 0.f ? rsqrtf(t) : 0.f;
  }
}

// ---------------- K2: colsum partials (vectorized ushort8) -------------------
__global__ void __launch_bounds__(256) colsum_kernel(
    const unsigned short* __restrict__ Abf, float* __restrict__ partial) {
  const int j0 = threadIdx.x * 8;
  const int i0 = blockIdx.x * 64;
  float s[8] = {0, 0, 0, 0, 0, 0, 0, 0};
  for (int i = 0; i < 64; i++) {
    ushort8v a = *(const ushort8v*)&Abf[(size_t)(i0 + i) * NN + j0];
#pragma unroll
    for (int e = 0; e < 8; e++) s[e] += b2f(a[e]);
  }
  float* p = partial + (size_t)blockIdx.x * NN + j0;
  *(float4*)p = make_float4(s[0], s[1], s[2], s[3]);
  *(float4*)(p + 4) = make_float4(s[4], s[5], s[6], s[7]);
}

// ---------------- K3: dc = rsqrt(colsum) -------------------------------------
__global__ void __launch_bounds__(256) dc_kernel(
    const float* __restrict__ partial, float* __restrict__ dc) {
  const int j = blockIdx.x * 256 + threadIdx.x;
  float s = 0.f;
#pragma unroll
  for (int p = 0; p < 32; p++) s += partial[(size_t)p * NN + j];
  dc[j] = s > 0.f ? rsqrtf(s) : 0.f;
}

// ---------------- split-K MFMA GEMM ------------------------------------------
// P[sk][m][n] = sum_{k in chunk sk} A[m][k] * B[n][k]
// A: bf16 [M][K], or (A_F32T) fp32 [K][lda] read transposed (A[m][k]=Av[k*lda+row0+m]).
// B: bf16 [N][K], or (B_F32) fp32 [N][K] (converted during staging).
// Block: BM=32 x BN=128, inner KC=128; 4 waves, one 32x32x16 mfma tile each.
// LDS stride 136 ushorts = 68 dwords == 4 (mod 32): frag ds_read_b128 hits each
// bank exactly 4x (conflict-minimal), rows 16B-aligned (272 = 17*16).
template <bool A_F32T, bool B_F32>
__global__ void __launch_bounds__(256) gemm_splitk_kernel(
    const void* __restrict__ Av, const void* __restrict__ Bv,
    float* __restrict__ P, int M, int N, int K, int Kc, int lda) {
  constexpr int SW = 136;
  __shared__ unsigned short As[32 * SW];
  __shared__ unsigned short Bs[128 * SW];
  const int tid = threadIdx.x;
  const int lane = tid & 63, wave = tid >> 6;
  const int l31 = lane & 31, half = lane >> 5;
  const int row0 = blockIdx.y * 32, col0 = blockIdx.x * 128;
  const int kbeg = blockIdx.z * Kc;

  float16v acc;
#pragma unroll
  for (int r = 0; r < 16; r++) acc[r] = 0.f;

  for (int k0 = 0; k0 < Kc; k0 += 128) {
    // ---- stage A tile: 32 rows(m) x 128 k
    if (A_F32T) {
      // source fp32 [K][lda], transpose in-flight. thread: k-row tid>>1, 16 cols.
      const int kidx = tid >> 1, nh = (tid & 1) * 16;
      const float* src = (const float*)Av + (size_t)(kbeg + k0 + kidx) * lda + row0 + nh;
      float4 v0 = ((const float4*)src)[0], v1 = ((const float4*)src)[1];
      float4 v2 = ((const float4*)src)[2], v3 = ((const float4*)src)[3];
      const float vv[16] = {v0.x, v0.y, v0.z, v0.w, v1.x, v1.y, v1.z, v1.w,
                            v2.x, v2.y, v2.z, v2.w, v3.x, v3.y, v3.z, v3.w};
#pragma unroll
      for (int e = 0; e < 16; e++) As[(nh + e) * SW + kidx] = f2b(vv[e]);
    } else {
      const unsigned short* Ab = (const unsigned short*)Av;
#pragma unroll
      for (int i = 0; i < 2; i++) {
        const int id = tid + i * 256;
        const int r = id >> 4, c = id & 15;
        *(ushort8v*)&As[r * SW + c * 8] =
            *(const ushort8v*)&Ab[(size_t)(row0 + r) * K + kbeg + k0 + c * 8];
      }
    }
    // ---- stage B panel: 128 rows(n) x 128 k = 2048 8-ushort chunks, 8/thread
#pragma unroll
    for (int i = 0; i < 8; i++) {
      const int id = tid + i * 256;
      const int r = id >> 4, c = id & 15;
      if (B_F32) {
        const float* bp = (const float*)Bv + (size_t)(col0 + r) * K + kbeg + k0 + c * 8;
        float4 u = *(const float4*)bp, v = *(const float4*)(bp + 4);
        ushort8v pk = {f2b(u.x), f2b(u.y), f2b(u.z), f2b(u.w),
                       f2b(v.x), f2b(v.y), f2b(v.z), f2b(v.w)};
        *(ushort8v*)&Bs[r * SW + c * 8] = pk;
      } else {
        *(ushort8v*)&Bs[r * SW + c * 8] =
            *(const ushort8v*)&((const unsigned short*)Bv)[(size_t)(col0 + r) * K + kbeg + k0 + c * 8];
      }
    }
    __syncthreads();
    // A frag: m=lane&31, k=(lane>>5)*8+j ; B frag: n=lane&31, same k
#pragma unroll
    for (int ks = 0; ks < 8; ks++) {
      short8v a = *(const short8v*)&As[l31 * SW + ks * 16 + half * 8];
      short8v b = *(const short8v*)&Bs[(wave * 32 + l31) * SW + ks * 16 + half * 8];
      acc = __builtin_amdgcn_mfma_f32_32x32x16_bf16(a, b, acc, 0, 0, 0);
    }
    __syncthreads();
  }
  // C/D: col = lane&31, row = (reg&3) + 8*(reg>>2) + 4*(lane>>5)
  float* Pb = P + ((size_t)blockIdx.z * M + row0) * N + col0 + wave * 32 + l31;
#pragma unroll
  for (int reg = 0; reg < 16; reg++) {
    const int m = (reg & 3) + 8 * (reg >> 2) + 4 * half;
    Pb[(size_t)m * N] = acc[reg];
  }
}

// ---------------- reduce GEMM1 partials -> XWT bf16 [256][2048], *dc[col] ----
__global__ void __launch_bounds__(256) reduce_xwt_kernel(
    const float* __restrict__ P, const float* __restrict__ dc,
    unsigned short* __restrict__ XWT) {
  const int t = blockIdx.x * 256 + threadIdx.x;
  const int i = t >> 8;            // output row (0..255)
  const int j0 = (t & 255) * 8;    // output col group
  float s[8] = {0, 0, 0, 0, 0, 0, 0, 0};
#pragma unroll
  for (int sk = 0; sk < 4; sk++) {
    const float* p = P + ((size_t)sk * 256 + i) * 2048 + j0;
    float4 u = *(const float4*)p, v = *(const float4*)(p + 4);
    s[0] += u.x; s[1] += u.y; s[2] += u.z; s[3] += u.w;
    s[4] += v.x; s[5] += v.y; s[6] += v.z; s[7] += v.w;
  }
  float4 d0 = *(const float4*)&dc[j0], d1 = *(const float4*)&dc[j0 + 4];
  ushort8v o = {f2b(s[0] * d0.x), f2b(s[1] * d0.y), f2b(s[2] * d0.z), f2b(s[3] * d0.w),
                f2b(s[4] * d1.x), f2b(s[5] * d1.y), f2b(s[6] * d1.z), f2b(s[7] * d1.w)};
  *(ushort8v*)&XWT[(size_t)i * 2048 + j0] = o;
}

// ---------------- fused tail: P2 -> T1(=dr*sum) -> hid(@Wl2+bl2) -> HW(@Wg2*dc)
__global__ void __launch_bounds__(256) tail_kernel(
    const float* __restrict__ P2, const float* __restrict__ dr,
    const float* __restrict__ dc, const float* __restrict__ Wl2,
    const float* __restrict__ bl2, const float* __restrict__ Wg2,
    float* __restrict__ hid, float* __restrict__ HW) {
  __shared__ float T1s[16][256];
  __shared__ float hidS[16][68];
  const int m0 = blockIdx.x * 16;
  const int tid = threadIdx.x;
  // phase 1: T1 rows (reduce 4 split-K partials, scale by dr)
#pragma unroll
  for (int i = 0; i < 16; i++) {
    const int idx = tid + i * 256;
    const int mi = idx >> 8, n = idx & 255;
    float s = 0.f;
#pragma unroll
    for (int sk = 0; sk < 4; sk++)
      s += P2[((size_t)sk * 2048 + m0 + mi) * 256 + n];
    T1s[mi][n] = s * dr[m0 + mi];
  }
  __syncthreads();
  // phase 2: hid[m][j] = T1[m][:] @ Wl2[:,j] + bl2[j]
  const int j = tid & 63, mg = tid >> 6;
  float h[4] = {bl2[j], bl2[j], bl2[j], bl2[j]};
  for (int n = 0; n < 256; n++) {
    float w = Wl2[(size_t)n * 64 + j];
#pragma unroll
    for (int r = 0; r < 4; r++) h[r] = fmaf(T1s[mg * 4 + r][n], w, h[r]);
  }
#pragma unroll
  for (int r = 0; r < 4; r++) {
    hid[(size_t)(m0 + mg * 4 + r) * 64 + j] = h[r];
    hidS[mg * 4 + r][j] = h[r];
  }
  __syncthreads();
  // phase 3: HW[m][c] = dc[m] * hid[m][:] @ Wg2[:,c]
  if (tid < 64) {
    const int r = tid >> 2, c = tid & 3;
    float s = 0.f;
#pragma unroll
    for (int jj = 0; jj < 64; jj++) s = fmaf(hidS[r][jj], Wg2[jj * 4 + c], s);
    HW[(size_t)(m0 + r) * 4 + c] = s * dc[m0 + r];
  }
}

// ---------------- out[i,:] = dr[i] * (Abf[i,:] @ HW) -------------------------
__global__ void __launch_bounds__(256) out_kernel(
    const unsigned short* __restrict__ Abf, const float* __restrict__ HW,
    const float* __restrict__ dr, float* __restrict__ outp) {
  const int i = blockIdx.x, tid = threadIdx.x;
  const ushort8v a8 = ((const ushort8v*)(Abf + (size_t)i * NN))[tid];
  const float4* hw4 = (const float4*)HW;
  const int j0 = tid * 8;
  float ax = 0.f, ay = 0.f, az = 0.f, aw = 0.f;
#pragma unroll
  for (int e = 0; e < 8; e++) {
    float a = b2f(a8[e]);
    float4 h = hw4[j0 + e];
    ax = fmaf(a, h.x, ax);
    ay = fmaf(a, h.y, ay);
    az = fmaf(a, h.z, az);
    aw = fmaf(a, h.w, aw);
  }
  __shared__ float red[4][256];
  red[0][tid] = ax; red[1][tid] = ay; red[2][tid] = az; red[3][tid] = aw;
  __syncthreads();
  for (int s = 128; s > 0; s >>= 1) {
    if (tid < s) {
      red[0][tid] += red[0][tid + s];
      red[1][tid] += red[1][tid + s];
      red[2][tid] += red[2][tid + s];
      red[3][tid] += red[3][tid + s];
    }
    __syncthreads();
  }
  if (tid < 4) outp[(size_t)i * 4 + tid] = dr[i] * red[tid][0];
}

extern "C" void kernel_launch(void* const* d_in, const int* in_sizes, int n_in,
                              void* d_out, int out_size, void* d_ws, size_t ws_size,
                              hipStream_t stream) {
  const float* x    = (const float*)d_in[0];
  const float* adj  = (const float*)d_in[1];
  const float* xdeg = (const float*)d_in[2];
  const float* ydeg = (const float*)d_in[3];
  const float* Wm1  = (const float*)d_in[4];
  const float* bm1  = (const float*)d_in[5];
  const float* Wm2  = (const float*)d_in[6];
  const float* bm2  = (const float*)d_in[7];
  const float* Wg1  = (const float*)d_in[8];
  const float* Wl2  = (const float*)d_in[9];
  const float* bl2  = (const float*)d_in[10];
  const float* Wg2  = (const float*)d_in[11];

  char* ws = (char*)d_ws;
  unsigned short* Abf  = (unsigned short*)(ws);              // 8 MiB [2048][2048]
  unsigned short* XWT  = (unsigned short*)(ws + 8388608);    // 1 MiB [256][2048]
  float* P    = (float*)(ws + 9437184);                      // 8 MiB split-K partials
  float* part = (float*)(ws + 18350080);                     // 256 KiB [32][2048]
  float* dr   = (float*)(ws + 18612224);
  float* dc   = (float*)(ws + 18620416);
  float* HW   = (float*)(ws + 18628608);                     // 32 KiB

  float* outp = (float*)d_out;             // output 0: [2048,4]
  float* hid  = (float*)d_out + 2048 * 4;  // output 1: [2048,64]

  edge_kernel<<<NN, 256, 0, stream>>>(adj, xdeg, ydeg, Wm1, bm1, Wm2, bm2, Abf, dr);
  colsum_kernel<<<32, 256, 0, stream>>>(Abf, part);
  dc_kernel<<<NN / 256, 256, 0, stream>>>(part, dc);
  // GEMM1: P[sk][i][j] partial of Wg1^T @ x^T  (M=256, N=2048, K=1024, SK=4)
  // A staged straight from fp32 Wg1 [1024][256] with in-LDS transpose.
  gemm_splitk_kernel<true, true><<<dim3(2048 / 128, 256 / 32, 4), 256, 0, stream>>>(
      Wg1, x, P, 256, 2048, 1024, 256, 256);
  reduce_xwt_kernel<<<256, 256, 0, stream>>>(P, dc, XWT);
  // GEMM2: P[sk][m][n] partial of Abf @ XWT^T  (M=2048, N=256, K=2048, SK=4)
  gemm_splitk_kernel<false, false><<<dim3(256 / 128, 2048 / 32, 4), 256, 0, stream>>>(
      Abf, XWT, P, 2048, 256, 2048, 512, 0);
  // tail: reduce + dr scale -> hid (d_out) and HW (= dc * hid @ Wg2)
  tail_kernel<<<2048 / 16, 256, 0, stream>>>(P, dr, dc, Wl2, bl2, Wg2, hid, HW);
  out_kernel<<<NN, 256, 0, stream>>>(Abf, HW, dr, outp);
}